// Round 7
// baseline (16.976 us; speedup 1.0000x reference)
//
#include <hip/hip_runtime.h>
#include <hip/hip_bf16.h>

// DenseKAN fused: out[b,o] = sum_i [ sum_k bases[b,i,k]*W[i,k,o] + silu(x[b,i]) ] * S[i,o] + bias[o]
// B=4096, D=128, U=128, cubic B-spline, 12 uniform knots -2.2..2.2 (h=0.4), x in [0,1).
// GEMM view: A(4096 x 1152) @ W2ext(1152 x 128); K = 1024 spline + 128 silu slots.
// Output f32. Wf[c][o][kk] bf16 staged in d_ws (prep), consumed fragment-contiguous (main).
//
// R7: main 512 -> 1024 blocks (16 rows x 32-unit quarter; 4 blocks/CU = 4 waves/SIMD)
//     to test the TLP-limited hypothesis; K-loop split into unrolled spline part +
//     explicit silu chunk for load hoisting/ILP.

typedef __attribute__((ext_vector_type(4))) float f32x4;
typedef __attribute__((ext_vector_type(8))) short vshort8;

__device__ __forceinline__ unsigned short f2bf(float f) {
    union { float f; unsigned u; } v; v.f = f;
    return (unsigned short)((v.u + 0x7FFFu + ((v.u >> 16) & 1u)) >> 16);
}

// ---------------------------------------------------------------------------
// prep: Wf[c][o][kk] (bf16): kglob=c*32+kk; kglob<1024 -> W[i][k][o]*S[i][o]
// (i=kglob>>3,k=kglob&7); kglob>=1024 -> S[kglob-1024][o] (silu slots).
// 72 blocks x 256. Thread u -> (c=u>>9, q=(u>>7)&3, o=u&127), 8 kk values.
// ---------------------------------------------------------------------------
__global__ __launch_bounds__(256) void kan_prep(
    const float* __restrict__ Ksp,   // (128,8,128)
    const float* __restrict__ S,     // (128,128)
    unsigned short* __restrict__ Wf) // (36,128,32) bf16
{
    const int u = blockIdx.x * 256 + threadIdx.x;   // 0..18431
    const int c = u >> 9;
    const int q = (u >> 7) & 3;
    const int o = u & 127;
    vshort8 w;
    if (c < 32) {
        const int i = c * 4 + q;
        const float s = S[i * 128 + o];
#pragma unroll
        for (int e = 0; e < 8; ++e)
            w[e] = (short)f2bf(Ksp[(size_t)(c * 32 + q * 8 + e) * 128 + o] * s);
    } else {
#pragma unroll
        for (int e = 0; e < 8; ++e) {
            const int i = (c - 32) * 32 + q * 8 + e;
            w[e] = (short)f2bf(S[i * 128 + o]);
        }
    }
    *reinterpret_cast<vshort8*>(Wf + (size_t)c * 4096 + o * 32 + q * 8) = w;
}

// ---------------------------------------------------------------------------
// main: 1024 blocks x 256. Block = 16 batch rows x 32 units (bid&3 -> quarter).
// 4 waves split the 36 K-chunks (wave w: c = w, w+4, ..., w+32).
// A-frag built in registers (closed-form uniform cubic B-spline; lane r0 = row,
// g = k-group -> i = c*4+g). B-frags: 16B loads from Wf. 2x mfma per chunk.
// C/D: lane(r0,g) reg v = D[4g+v][16n+r0] (m89; HW-probe-confirmed r2).
// ---------------------------------------------------------------------------
__global__ __launch_bounds__(256) void kan_main(
    const float* __restrict__ x,          // (4096,128)
    const unsigned short* __restrict__ Wf,// (36,128,32) bf16
    const float* __restrict__ bias,       // (128)
    float* __restrict__ out)              // (4096,128) f32
{
    const int PAD = 132;    // x/sl row stride (floats)
    const int CPAD = 36;    // part row stride (floats)
    __shared__ float x_lds[16 * PAD];
    __shared__ float sl_lds[16 * PAD];
    __shared__ float part[4 * 16 * CPAD];

    const int tid = threadIdx.x;
    const int rb = (blockIdx.x >> 2) * 16;
    const int ob = (blockIdx.x & 3) * 32;

    // ---- stage x + silu(x), 16 rows x 128 (coalesced float4) ----
#pragma unroll
    for (int q = 0; q < 2; ++q) {
        int f4 = tid + q * 256;            // 0..511
        int row = f4 >> 5, c4 = f4 & 31;
        float4 v = reinterpret_cast<const float4*>(x + (size_t)(rb + row) * 128)[c4];
        float4 s;
        s.x = v.x / (1.f + __expf(-v.x));
        s.y = v.y / (1.f + __expf(-v.y));
        s.z = v.z / (1.f + __expf(-v.z));
        s.w = v.w / (1.f + __expf(-v.w));
        reinterpret_cast<float4*>(&x_lds[row * PAD])[c4] = v;
        reinterpret_cast<float4*>(&sl_lds[row * PAD])[c4] = s;
    }
    __syncthreads();

    const int w = tid >> 6;
    const int lane = tid & 63;
    const int r0 = lane & 15;              // A row / D col-within-frag
    const int g = lane >> 4;               // k-group (8 k per group)

    f32x4 acc[2];
#pragma unroll
    for (int n = 0; n < 2; ++n) { f32x4 z = {0.f, 0.f, 0.f, 0.f}; acc[n] = z; }

    // ---- 8 spline chunks (fully unrolled: loads hoistable across iters) ----
#pragma unroll
    for (int t = 0; t < 8; ++t) {
        const int c = w + 4 * t;           // this wave's K-chunk
        const int i = c * 4 + g;           // input dim for this lane's k-group
        const float xv = x_lds[r0 * PAD + i];
        const float tt = (xv + 2.2f) * 2.5f;
        const float jf = floorf(tt);
        const int j = (int)jf;             // in {5,6,7} for x in [0,1)
        const float u = tt - jf;
        const float u2 = u * u, u3 = u2 * u;
        const float n0 = (1.f / 6.f) * (1.f - 3.f * u + 3.f * u2 - u3);
        const float n1 = (1.f / 6.f) * (3.f * u3 - 6.f * u2 + 4.f);
        const float n2 = (1.f / 6.f) * (-3.f * u3 + 3.f * u2 + 3.f * u + 1.f);
        const float n3 = (1.f / 6.f) * u3;
        const bool j5 = (j == 5), j6 = (j == 6);
        const float s2 = j5 ? n0 : 0.f;
        const float s3 = j5 ? n1 : (j6 ? n0 : 0.f);
        const float s4 = j5 ? n2 : (j6 ? n1 : n0);
        const float s5 = j5 ? n3 : (j6 ? n2 : n1);
        const float s6 = j5 ? 0.f : (j6 ? n3 : n2);
        const float s7 = (!j5 && !j6) ? n3 : 0.f;
        vshort8 af;
        af[0] = 0; af[1] = 0;
        af[2] = (short)f2bf(s2);
        af[3] = (short)f2bf(s3);
        af[4] = (short)f2bf(s4);
        af[5] = (short)f2bf(s5);
        af[6] = (short)f2bf(s6);
        af[7] = (short)f2bf(s7);

        const unsigned short* bp = Wf + (size_t)c * 4096 + (ob + r0) * 32 + 8 * g;
#pragma unroll
        for (int n = 0; n < 2; ++n) {
            vshort8 bf = *reinterpret_cast<const vshort8*>(bp + n * 512);
            acc[n] = __builtin_amdgcn_mfma_f32_16x16x32_bf16(af, bf, acc[n], 0, 0, 0);
        }
    }

    // ---- silu chunk: c = 32 + w; A[b][kk] = silu(x[b][w*32+kk]) ----
    {
        const int c = 32 + w;
        const int i0 = w * 32 + 8 * g;
        const float4* sp = reinterpret_cast<const float4*>(&sl_lds[r0 * PAD + i0]);
        const float4 a = sp[0], b = sp[1];
        vshort8 af;
        af[0] = (short)f2bf(a.x); af[1] = (short)f2bf(a.y);
        af[2] = (short)f2bf(a.z); af[3] = (short)f2bf(a.w);
        af[4] = (short)f2bf(b.x); af[5] = (short)f2bf(b.y);
        af[6] = (short)f2bf(b.z); af[7] = (short)f2bf(b.w);

        const unsigned short* bp = Wf + (size_t)c * 4096 + (ob + r0) * 32 + 8 * g;
#pragma unroll
        for (int n = 0; n < 2; ++n) {
            vshort8 bf = *reinterpret_cast<const vshort8*>(bp + n * 512);
            acc[n] = __builtin_amdgcn_mfma_f32_16x16x32_bf16(af, bf, acc[n], 0, 0, 0);
        }
    }

    // lane(r0,g) reg v holds D[row=4g+v][col=16n+r0]
#pragma unroll
    for (int n = 0; n < 2; ++n)
#pragma unroll
        for (int v2 = 0; v2 < 4; ++v2)
            part[w * 16 * CPAD + (g * 4 + v2) * CPAD + n * 16 + r0] = acc[n][v2];
    __syncthreads();

    // ---- reduce 4 waves + bias, f32 store (32-wide rows) ----
#pragma unroll
    for (int q = 0; q < 2; ++q) {
        int f = tid + q * 256;             // 0..511
        int row = f >> 5, col = f & 31;
        float s = part[0 * 16 * CPAD + row * CPAD + col]
                + part[1 * 16 * CPAD + row * CPAD + col]
                + part[2 * 16 * CPAD + row * CPAD + col]
                + part[3 * 16 * CPAD + row * CPAD + col]
                + bias[ob + col];
        out[(size_t)(rb + row) * 128 + ob + col] = s;
    }
}

// ---------------------------------------------------------------------------
// fallback (only if ws too small): exact scalar f32 path.
// ---------------------------------------------------------------------------
__global__ __launch_bounds__(128) void kan_fallback(
    const float* __restrict__ x, const float* __restrict__ Ksp,
    const float* __restrict__ S, const float* __restrict__ bias,
    float* __restrict__ out)
{
    __shared__ float n_lds[4][128];
    __shared__ int   j_lds[128];
    __shared__ float sil_lds[128];

    const int b = blockIdx.x, o = threadIdx.x;
    {
        const float xv = x[(size_t)b * 128 + o];
        const float tt = (xv + 2.2f) * 2.5f;
        const float jf = floorf(tt);
        const float u = tt - jf;
        const float u2 = u * u, u3 = u2 * u;
        n_lds[0][o] = (1.f / 6.f) * (1.f - 3.f * u + 3.f * u2 - u3);
        n_lds[1][o] = (1.f / 6.f) * (3.f * u3 - 6.f * u2 + 4.f);
        n_lds[2][o] = (1.f / 6.f) * (-3.f * u3 + 3.f * u2 + 3.f * u + 1.f);
        n_lds[3][o] = (1.f / 6.f) * u3;
        j_lds[o] = (int)jf;
        sil_lds[o] = xv / (1.f + __expf(-xv));
    }
    __syncthreads();

    float acc = 0.f;
    for (int i = 0; i < 128; ++i) {
        const float* wp = Ksp + ((size_t)(i * 8) + (j_lds[i] - 3)) * 128 + o;
        float sp = n_lds[0][i] * wp[0]
                 + n_lds[1][i] * wp[128]
                 + n_lds[2][i] * wp[256]
                 + n_lds[3][i] * wp[384];
        acc += (sp + sil_lds[i]) * S[i * 128 + o];
    }
    out[(size_t)b * 128 + o] = acc + bias[o];
}

extern "C" void kernel_launch(void* const* d_in, const int* in_sizes, int n_in,
                              void* d_out, int out_size, void* d_ws, size_t ws_size,
                              hipStream_t stream) {
    // Resolve inputs robustly (element counts or bytes).
    int div = 1;
    for (int i = 0; i < n_in; ++i)
        if (in_sizes[i] == 2097152) { div = 4; break; }
    const float *x = nullptr, *Ksp = nullptr, *S = nullptr, *bias = nullptr;
    for (int i = 0; i < n_in; ++i) {
        switch (in_sizes[i] / div) {
            case 4096 * 128:    x    = (const float*)d_in[i]; break;
            case 128 * 8 * 128: Ksp  = (const float*)d_in[i]; break;
            case 128 * 128:     S    = (const float*)d_in[i]; break;
            case 128:           bias = (const float*)d_in[i]; break;
        }
    }
    if (!x || !Ksp || !S || !bias) {
        x = (const float*)d_in[0]; Ksp = (const float*)d_in[1];
        S = (const float*)d_in[2]; bias = (const float*)d_in[3];
    }
    float* out = (float*)d_out;

    const size_t wf_bytes = (size_t)36 * 128 * 32 * sizeof(unsigned short); // 288 KB
    if (ws_size >= wf_bytes) {
        unsigned short* Wf = (unsigned short*)d_ws;
        kan_prep<<<72, 256, 0, stream>>>(Ksp, S, Wf);
        kan_main<<<1024, 256, 0, stream>>>(x, Wf, bias, out);
    } else {
        kan_fallback<<<4096, 128, 0, stream>>>(x, Ksp, S, bias, out);
    }
}

// Round 9
// 14.575 us; speedup vs baseline: 1.1647x; 1.1647x over previous
//
#include <hip/hip_runtime.h>
#include <hip/hip_bf16.h>

// DenseKAN fused single-kernel:
// out[b,o] = sum_i [ sum_k bases[b,i,k]*W[i,k,o] + silu(x[b,i]) ] * S[i,o] + bias[o]
// B=4096, D=128, U=128, cubic B-spline, 12 uniform knots -2.2..2.2 (h=0.4), x in [0,1).
// GEMM view: A(4096 x 1152) @ W2ext(1152 x 128); K = 1024 spline + 128 silu slots.
//
// R9 = R8 with the bit_cast fix: pack two RNE bf16 halves via integer ops.
//  - ONE kernel node (prep eliminated); B-frags built on the fly from Ksp/S.
//  - frag element e == kbasis: lane's 8 B-values = Ksp[i][0..7][oc]*S[i][oc],
//    all at immediate offsets (e*512B <= 3584) off a single base pointer.
//  - spline slots 0,1 are dead (j in {5,6,7} -> A==0 there): B loads skipped.

typedef __attribute__((ext_vector_type(4))) float f32x4;
typedef __attribute__((ext_vector_type(8))) short vshort8;
typedef __attribute__((ext_vector_type(4))) unsigned int vuint4;

__device__ __forceinline__ unsigned int bfbits(float f) {
    union { float f; unsigned u; } v; v.f = f;
    return (v.u + 0x7FFFu + ((v.u >> 16) & 1u)) >> 16;   // RNE, matches _rn
}
__device__ __forceinline__ unsigned int f2bf2(float lo, float hi) {
    return (bfbits(hi) << 16) | bfbits(lo);
}

// ---------------------------------------------------------------------------
// 512 blocks x 256 threads. Block = 16 batch rows x 64 units (bid&1 -> half).
// 4 waves split the 36 K-chunks (wave w: c = w, w+4, ..., w+32).
// A-frag in registers (closed-form uniform cubic B-spline; lane r0 = row,
// g = k-group -> i = c*4+g). B-frags from Ksp/S directly. 4x mfma per chunk.
// C/D: lane(r0,g) reg v = D[4g+v][16n+r0] (m89; HW-probe-confirmed r2).
// ---------------------------------------------------------------------------
__global__ __launch_bounds__(256) void kan_fused(
    const float* __restrict__ x,     // (4096,128)
    const float* __restrict__ Ksp,   // (128,8,128)
    const float* __restrict__ S,     // (128,128)
    const float* __restrict__ bias,  // (128)
    float* __restrict__ out)         // (4096,128) f32
{
    const int PAD = 132;    // x/sl row stride (floats)
    const int CPAD = 68;    // part row stride (floats)
    __shared__ float x_lds[16 * PAD];
    __shared__ float sl_lds[16 * PAD];
    __shared__ float part[4 * 16 * CPAD];

    const int tid = threadIdx.x;
    const int rb = (blockIdx.x >> 1) * 16;
    const int ob = (blockIdx.x & 1) * 64;

    // ---- stage x + silu(x), 16 rows x 128 (coalesced float4) ----
#pragma unroll
    for (int q = 0; q < 2; ++q) {
        int f4 = tid + q * 256;            // 0..511
        int row = f4 >> 5, c4 = f4 & 31;
        float4 v = reinterpret_cast<const float4*>(x + (size_t)(rb + row) * 128)[c4];
        float4 s;
        s.x = v.x / (1.f + __expf(-v.x));
        s.y = v.y / (1.f + __expf(-v.y));
        s.z = v.z / (1.f + __expf(-v.z));
        s.w = v.w / (1.f + __expf(-v.w));
        reinterpret_cast<float4*>(&x_lds[row * PAD])[c4] = v;
        reinterpret_cast<float4*>(&sl_lds[row * PAD])[c4] = s;
    }
    __syncthreads();

    const int w = tid >> 6;
    const int lane = tid & 63;
    const int r0 = lane & 15;              // A row / D col-within-frag
    const int g = lane >> 4;               // k-group (8 k per group)

    f32x4 acc[4];
#pragma unroll
    for (int n = 0; n < 4; ++n) { f32x4 z = {0.f, 0.f, 0.f, 0.f}; acc[n] = z; }

    // ---- 8 spline chunks ----
#pragma unroll
    for (int t = 0; t < 8; ++t) {
        const int c = w + 4 * t;           // this wave's K-chunk
        const int i = c * 4 + g;           // input dim for this lane's k-group
        const float xv = x_lds[r0 * PAD + i];
        const float tt = (xv + 2.2f) * 2.5f;
        const float jf = floorf(tt);
        const int j = (int)jf;             // in {5,6,7} for x in [0,1)
        const float u = tt - jf;
        const float u2 = u * u, u3 = u2 * u;
        const float n0 = (1.f / 6.f) * (1.f - 3.f * u + 3.f * u2 - u3);
        const float n1 = (1.f / 6.f) * (3.f * u3 - 6.f * u2 + 4.f);
        const float n2 = (1.f / 6.f) * (-3.f * u3 + 3.f * u2 + 3.f * u + 1.f);
        const float n3 = (1.f / 6.f) * u3;
        const bool j5 = (j == 5), j6 = (j == 6);
        const float s2 = j5 ? n0 : 0.f;
        const float s3 = j5 ? n1 : (j6 ? n0 : 0.f);
        const float s4 = j5 ? n2 : (j6 ? n1 : n0);
        const float s5 = j5 ? n3 : (j6 ? n2 : n1);
        const float s6 = j5 ? 0.f : (j6 ? n3 : n2);
        const float s7 = (!j5 && !j6) ? n3 : 0.f;
        vuint4 au;
        au[0] = 0;
        au[1] = f2bf2(s2, s3);
        au[2] = f2bf2(s4, s5);
        au[3] = f2bf2(s6, s7);
        const vshort8 af = __builtin_bit_cast(vshort8, au);

        const float* kp = Ksp + (size_t)i * 1024;   // (i, kbasis, o); kbasis stride 128
        const float* sp2 = S + i * 128;
#pragma unroll
        for (int n = 0; n < 4; ++n) {
            const int oc = ob + 16 * n + r0;
            const float sv = sp2[oc];
            const float* kb = kp + oc;              // e*512B immediate offsets
            vuint4 bu;
            bu[0] = 0;                               // slots 0,1 dead (A==0 there)
            bu[1] = f2bf2(kb[2 * 128] * sv, kb[3 * 128] * sv);
            bu[2] = f2bf2(kb[4 * 128] * sv, kb[5 * 128] * sv);
            bu[3] = f2bf2(kb[6 * 128] * sv, kb[7 * 128] * sv);
            const vshort8 bf = __builtin_bit_cast(vshort8, bu);
            acc[n] = __builtin_amdgcn_mfma_f32_16x16x32_bf16(af, bf, acc[n], 0, 0, 0);
        }
    }

    // ---- silu chunk: c = 32 + w; A[b][kk] = silu(x[b][w*32+kk]), B = S rows ----
    {
        const int i0 = w * 32 + 8 * g;
        const float4* sp = reinterpret_cast<const float4*>(&sl_lds[r0 * PAD + i0]);
        const float4 a = sp[0], b = sp[1];
        vuint4 au;
        au[0] = f2bf2(a.x, a.y);
        au[1] = f2bf2(a.z, a.w);
        au[2] = f2bf2(b.x, b.y);
        au[3] = f2bf2(b.z, b.w);
        const vshort8 af = __builtin_bit_cast(vshort8, au);

        const float* sb = S + (size_t)i0 * 128;     // rows i0..i0+7, e*512B offsets
#pragma unroll
        for (int n = 0; n < 4; ++n) {
            const int oc = ob + 16 * n + r0;
            const float* sc = sb + oc;
            vuint4 bu;
            bu[0] = f2bf2(sc[0 * 128], sc[1 * 128]);
            bu[1] = f2bf2(sc[2 * 128], sc[3 * 128]);
            bu[2] = f2bf2(sc[4 * 128], sc[5 * 128]);
            bu[3] = f2bf2(sc[6 * 128], sc[7 * 128]);
            const vshort8 bf = __builtin_bit_cast(vshort8, bu);
            acc[n] = __builtin_amdgcn_mfma_f32_16x16x32_bf16(af, bf, acc[n], 0, 0, 0);
        }
    }

    // lane(r0,g) reg v holds D[row=4g+v][col=16n+r0]
#pragma unroll
    for (int n = 0; n < 4; ++n)
#pragma unroll
        for (int v2 = 0; v2 < 4; ++v2)
            part[w * 16 * CPAD + (g * 4 + v2) * CPAD + n * 16 + r0] = acc[n][v2];
    __syncthreads();

    // ---- reduce 4 waves + bias, f32 store (64-wide rows, coalesced) ----
#pragma unroll
    for (int q = 0; q < 4; ++q) {
        int f = tid + q * 256;             // 0..1023
        int row = f >> 6, col = f & 63;
        float s = part[0 * 16 * CPAD + row * CPAD + col]
                + part[1 * 16 * CPAD + row * CPAD + col]
                + part[2 * 16 * CPAD + row * CPAD + col]
                + part[3 * 16 * CPAD + row * CPAD + col]
                + bias[ob + col];
        out[(size_t)(rb + row) * 128 + ob + col] = s;
    }
}

extern "C" void kernel_launch(void* const* d_in, const int* in_sizes, int n_in,
                              void* d_out, int out_size, void* d_ws, size_t ws_size,
                              hipStream_t stream) {
    // Resolve inputs robustly (element counts or bytes).
    int div = 1;
    for (int i = 0; i < n_in; ++i)
        if (in_sizes[i] == 2097152) { div = 4; break; }
    const float *x = nullptr, *Ksp = nullptr, *S = nullptr, *bias = nullptr;
    for (int i = 0; i < n_in; ++i) {
        switch (in_sizes[i] / div) {
            case 4096 * 128:    x    = (const float*)d_in[i]; break;
            case 128 * 8 * 128: Ksp  = (const float*)d_in[i]; break;
            case 128 * 128:     S    = (const float*)d_in[i]; break;
            case 128:           bias = (const float*)d_in[i]; break;
        }
    }
    if (!x || !Ksp || !S || !bias) {
        x = (const float*)d_in[0]; Ksp = (const float*)d_in[1];
        S = (const float*)d_in[2]; bias = (const float*)d_in[3];
    }
    float* out = (float*)d_out;

    kan_fused<<<512, 256, 0, stream>>>(x, Ksp, S, bias, out);
}

// Round 10
// 11.753 us; speedup vs baseline: 1.4444x; 1.2401x over previous
//
#include <hip/hip_runtime.h>
#include <hip/hip_bf16.h>

// DenseKAN fused single-kernel:
// out[b,o] = sum_i [ sum_k bases[b,i,k]*W[i,k,o] + silu(x[b,i]) ] * S[i,o] + bias[o]
// B=4096, D=128, U=128, cubic B-spline, 12 uniform knots -2.2..2.2 (h=0.4), x in [0,1).
// GEMM view: A(4096 x 1152) @ W2ext(1152 x 128); K = 1024 spline + 128 silu slots.
//
// R10: 256 blocks x 512 threads (8 waves). Block = 32 rows x 64 units.
//  - Wave w owns K-chunks c = 4w..4w+3 (+ silu chunk 32+w for w<4).
//  - Per chunk: B-frags built ONCE in registers, reused across TWO 16-row
//    sub-tiles (halves W L2 re-reads: ~134 MB -> ~72 MB, and B-build VALU).
//  - Epilogue: 8-way wave reduce through LDS, per row-tile sequentially.

typedef __attribute__((ext_vector_type(4))) float f32x4;
typedef __attribute__((ext_vector_type(8))) short vshort8;
typedef __attribute__((ext_vector_type(4))) unsigned int vuint4;

__device__ __forceinline__ unsigned int bfbits(float f) {
    union { float f; unsigned u; } v; v.f = f;
    return (v.u + 0x7FFFu + ((v.u >> 16) & 1u)) >> 16;   // RNE
}
__device__ __forceinline__ unsigned int f2bf2(float lo, float hi) {
    return (bfbits(hi) << 16) | bfbits(lo);
}

// ---------------------------------------------------------------------------
// C/D mapping (m89; HW-probe-confirmed r2): lane(r0,g) reg v = D[4g+v][16n+r0].
// ---------------------------------------------------------------------------
__global__ __launch_bounds__(512) void kan_fused(
    const float* __restrict__ x,     // (4096,128)
    const float* __restrict__ Ksp,   // (128,8,128)
    const float* __restrict__ S,     // (128,128)
    const float* __restrict__ bias,  // (128)
    float* __restrict__ out)         // (4096,128) f32
{
    const int PAD = 132;    // x/sl row stride (floats)
    const int CPAD = 68;    // part row stride (floats)
    __shared__ float x_lds[32 * PAD];     // 16.9 KB
    __shared__ float sl_lds[32 * PAD];    // 16.9 KB
    __shared__ float part[8 * 16 * CPAD]; // 34.8 KB

    const int tid = threadIdx.x;
    const int rb = (blockIdx.x >> 1) * 32;
    const int ob = (blockIdx.x & 1) * 64;

    // ---- stage x + silu(x): 32 rows x 128 (1024 float4 over 512 threads) ----
#pragma unroll
    for (int q = 0; q < 2; ++q) {
        int f4 = tid + q * 512;            // 0..1023
        int row = f4 >> 5, c4 = f4 & 31;
        float4 v = reinterpret_cast<const float4*>(x + (size_t)(rb + row) * 128)[c4];
        float4 s;
        s.x = v.x / (1.f + __expf(-v.x));
        s.y = v.y / (1.f + __expf(-v.y));
        s.z = v.z / (1.f + __expf(-v.z));
        s.w = v.w / (1.f + __expf(-v.w));
        reinterpret_cast<float4*>(&x_lds[row * PAD])[c4] = v;
        reinterpret_cast<float4*>(&sl_lds[row * PAD])[c4] = s;
    }
    __syncthreads();

    const int w = tid >> 6;                // 0..7
    const int lane = tid & 63;
    const int r0 = lane & 15;              // A row / D col-within-frag
    const int g = lane >> 4;               // k-group (8 k per group)

    f32x4 acc[2][4];
#pragma unroll
    for (int rt = 0; rt < 2; ++rt)
#pragma unroll
        for (int n = 0; n < 4; ++n) { f32x4 z = {0.f, 0.f, 0.f, 0.f}; acc[rt][n] = z; }

    // ---- 4 spline chunks: c = 4w+t; B built once, reused for 2 row-tiles ----
#pragma unroll
    for (int t = 0; t < 4; ++t) {
        const int c = w * 4 + t;
        const int i = c * 4 + g;           // input dim for this lane's k-group

        const float* kp = Ksp + (size_t)i * 1024;   // (i, kbasis, o)
        const float* sp2 = S + i * 128;
        vshort8 bfr[4];
#pragma unroll
        for (int n = 0; n < 4; ++n) {
            const int oc = ob + 16 * n + r0;
            const float sv = sp2[oc];
            const float* kb = kp + oc;              // kbasis stride 128 (512B imm)
            vuint4 bu;
            bu[0] = 0;                               // slots 0,1 dead (A==0 there)
            bu[1] = f2bf2(kb[2 * 128] * sv, kb[3 * 128] * sv);
            bu[2] = f2bf2(kb[4 * 128] * sv, kb[5 * 128] * sv);
            bu[3] = f2bf2(kb[6 * 128] * sv, kb[7 * 128] * sv);
            bfr[n] = __builtin_bit_cast(vshort8, bu);
        }

#pragma unroll
        for (int rt = 0; rt < 2; ++rt) {
            const float xv = x_lds[(rt * 16 + r0) * PAD + i];
            const float tt = (xv + 2.2f) * 2.5f;
            const float jf = floorf(tt);
            const int j = (int)jf;         // in {5,6,7} for x in [0,1)
            const float u = tt - jf;
            const float u2 = u * u, u3 = u2 * u;
            const float n0 = (1.f / 6.f) * (1.f - 3.f * u + 3.f * u2 - u3);
            const float n1 = (1.f / 6.f) * (3.f * u3 - 6.f * u2 + 4.f);
            const float n2 = (1.f / 6.f) * (-3.f * u3 + 3.f * u2 + 3.f * u + 1.f);
            const float n3 = (1.f / 6.f) * u3;
            const bool j5 = (j == 5), j6 = (j == 6);
            const float s2 = j5 ? n0 : 0.f;
            const float s3 = j5 ? n1 : (j6 ? n0 : 0.f);
            const float s4 = j5 ? n2 : (j6 ? n1 : n0);
            const float s5 = j5 ? n3 : (j6 ? n2 : n1);
            const float s6 = j5 ? 0.f : (j6 ? n3 : n2);
            const float s7 = (!j5 && !j6) ? n3 : 0.f;
            vuint4 au;
            au[0] = 0;
            au[1] = f2bf2(s2, s3);
            au[2] = f2bf2(s4, s5);
            au[3] = f2bf2(s6, s7);
            const vshort8 af = __builtin_bit_cast(vshort8, au);
#pragma unroll
            for (int n = 0; n < 4; ++n)
                acc[rt][n] = __builtin_amdgcn_mfma_f32_16x16x32_bf16(af, bfr[n], acc[rt][n], 0, 0, 0);
        }
    }

    // ---- silu chunk (waves 0..3): c = 32+w; A = silu rows, B = S rows ----
    if (w < 4) {
        const int i0 = w * 32 + 8 * g;
        const float* sb = S + (size_t)i0 * 128;
        vshort8 bfr[4];
#pragma unroll
        for (int n = 0; n < 4; ++n) {
            const int oc = ob + 16 * n + r0;
            const float* sc = sb + oc;
            vuint4 bu;
            bu[0] = f2bf2(sc[0 * 128], sc[1 * 128]);
            bu[1] = f2bf2(sc[2 * 128], sc[3 * 128]);
            bu[2] = f2bf2(sc[4 * 128], sc[5 * 128]);
            bu[3] = f2bf2(sc[6 * 128], sc[7 * 128]);
            bfr[n] = __builtin_bit_cast(vshort8, bu);
        }
#pragma unroll
        for (int rt = 0; rt < 2; ++rt) {
            const float4* sp = reinterpret_cast<const float4*>(&sl_lds[(rt * 16 + r0) * PAD + i0]);
            const float4 a = sp[0], b = sp[1];
            vuint4 au;
            au[0] = f2bf2(a.x, a.y);
            au[1] = f2bf2(a.z, a.w);
            au[2] = f2bf2(b.x, b.y);
            au[3] = f2bf2(b.z, b.w);
            const vshort8 af = __builtin_bit_cast(vshort8, au);
#pragma unroll
            for (int n = 0; n < 4; ++n)
                acc[rt][n] = __builtin_amdgcn_mfma_f32_16x16x32_bf16(af, bfr[n], acc[rt][n], 0, 0, 0);
        }
    }

    // ---- epilogue: per row-tile, 8-way wave reduce + bias, f32 store ----
#pragma unroll
    for (int rt = 0; rt < 2; ++rt) {
        __syncthreads();                   // part[] free to overwrite
        // lane(r0,g) reg v holds D[row=4g+v][col=16n+r0]
#pragma unroll
        for (int n = 0; n < 4; ++n)
#pragma unroll
            for (int v2 = 0; v2 < 4; ++v2)
                part[w * 16 * CPAD + (g * 4 + v2) * CPAD + n * 16 + r0] = acc[rt][n][v2];
        __syncthreads();
#pragma unroll
        for (int q = 0; q < 2; ++q) {
            int f = tid + q * 512;         // 0..1023
            int row = f >> 6, col = f & 63;
            float s = bias[ob + col];
#pragma unroll
            for (int ww = 0; ww < 8; ++ww)
                s += part[ww * 16 * CPAD + row * CPAD + col];
            out[(size_t)(rb + rt * 16 + row) * 128 + ob + col] = s;
        }
    }
}

extern "C" void kernel_launch(void* const* d_in, const int* in_sizes, int n_in,
                              void* d_out, int out_size, void* d_ws, size_t ws_size,
                              hipStream_t stream) {
    // Resolve inputs robustly (element counts or bytes).
    int div = 1;
    for (int i = 0; i < n_in; ++i)
        if (in_sizes[i] == 2097152) { div = 4; break; }
    const float *x = nullptr, *Ksp = nullptr, *S = nullptr, *bias = nullptr;
    for (int i = 0; i < n_in; ++i) {
        switch (in_sizes[i] / div) {
            case 4096 * 128:    x    = (const float*)d_in[i]; break;
            case 128 * 8 * 128: Ksp  = (const float*)d_in[i]; break;
            case 128 * 128:     S    = (const float*)d_in[i]; break;
            case 128:           bias = (const float*)d_in[i]; break;
        }
    }
    if (!x || !Ksp || !S || !bias) {
        x = (const float*)d_in[0]; Ksp = (const float*)d_in[1];
        S = (const float*)d_in[2]; bias = (const float*)d_in[3];
    }
    float* out = (float*)d_out;

    kan_fused<<<256, 512, 0, stream>>>(x, Ksp, S, bias, out);
}